// Round 1
// baseline (812.819 us; speedup 1.0000x reference)
//
#include <hip/hip_runtime.h>
#include <cfloat>

#define BB 8
#define DD 256
#define NN 4096
#define TT 1024
constexpr float SCALE = 0.0625f;   // 1/sqrt(256)

// ---------------- K1: S = scale * K^T Q  (per batch) ----------------
// tile 128(n) x 128(t), block 256, micro 8x8, k-chunk 8
__global__ __launch_bounds__(256) void gemm_scores(const float* __restrict__ Kp,
                                                   const float* __restrict__ Qp,
                                                   float* __restrict__ S) {
  const int b = blockIdx.z;
  const int n0 = blockIdx.y * 128;
  const int t0 = blockIdx.x * 128;
  const int tid = threadIdx.x;
  const int tx = tid & 15, ty = tid >> 4;

  __shared__ float Kt[8][128];
  __shared__ float Qt[8][128];

  float acc[8][8];
#pragma unroll
  for (int i = 0; i < 8; ++i)
#pragma unroll
    for (int j = 0; j < 8; ++j) acc[i][j] = 0.f;

  const int lin = tid * 4;
  const int lkk = lin >> 7;     // 0..7
  const int lcol = lin & 127;   // 0..124 step 4

  const float* Kbase = Kp + (size_t)b * DD * NN;
  const float* Qbase = Qp + (size_t)b * DD * TT;

  for (int dd0 = 0; dd0 < DD; dd0 += 8) {
    float4 kv = *(const float4*)(Kbase + (size_t)(dd0 + lkk) * NN + n0 + lcol);
    float4 qv = *(const float4*)(Qbase + (size_t)(dd0 + lkk) * TT + t0 + lcol);
    __syncthreads();
    *(float4*)&Kt[lkk][lcol] = kv;
    *(float4*)&Qt[lkk][lcol] = qv;
    __syncthreads();
#pragma unroll
    for (int kk = 0; kk < 8; ++kk) {
      float4 a0 = *(float4*)&Kt[kk][ty * 4];
      float4 a1 = *(float4*)&Kt[kk][64 + ty * 4];
      float4 b0 = *(float4*)&Qt[kk][tx * 4];
      float4 b1 = *(float4*)&Qt[kk][64 + tx * 4];
      float av[8] = {a0.x, a0.y, a0.z, a0.w, a1.x, a1.y, a1.z, a1.w};
      float bv[8] = {b0.x, b0.y, b0.z, b0.w, b1.x, b1.y, b1.z, b1.w};
#pragma unroll
      for (int i = 0; i < 8; ++i)
#pragma unroll
        for (int j = 0; j < 8; ++j) acc[i][j] += av[i] * bv[j];
    }
  }

#pragma unroll
  for (int i = 0; i < 8; ++i) {
    int r = n0 + ((i < 4) ? (ty * 4 + i) : (64 + ty * 4 + i - 4));
    float* dst = S + ((size_t)b * NN + r) * TT + t0;
    float4 v0 = make_float4(acc[i][0] * SCALE, acc[i][1] * SCALE,
                            acc[i][2] * SCALE, acc[i][3] * SCALE);
    float4 v1 = make_float4(acc[i][4] * SCALE, acc[i][5] * SCALE,
                            acc[i][6] * SCALE, acc[i][7] * SCALE);
    *(float4*)(dst + tx * 4) = v0;
    *(float4*)(dst + 64 + tx * 4) = v1;
  }
}

// ---------------- K2a: partial softmax stats over 512-key chunks ----------------
__global__ __launch_bounds__(256) void stats_partial(const float* __restrict__ S,
                                                     float* __restrict__ mPart,
                                                     float* __restrict__ lPart,
                                                     int* __restrict__ iPart) {
  const int tid = threadIdx.x;
  const int tx = tid & 63, ty = tid >> 6;
  const int b = blockIdx.z;
  const int t = blockIdx.x * 64 + tx;
  const int nbase = blockIdx.y * 512;

  float m = -FLT_MAX;
  float l = 0.f;
  int idx = 0;
  const float* col = S + (size_t)b * NN * TT + t;
  for (int n = nbase + ty; n < nbase + 512; n += 4) {
    float s = col[(size_t)n * TT];
    if (s > m) { l = l * expf(m - s) + 1.0f; m = s; idx = n; }
    else        l += expf(s - m);
  }
  __shared__ float sm[4][64], sl[4][64];
  __shared__ int si[4][64];
  sm[ty][tx] = m; sl[ty][tx] = l; si[ty][tx] = idx;
  __syncthreads();
  if (ty == 0) {
#pragma unroll
    for (int k = 1; k < 4; ++k) {
      float m2 = sm[k][tx], l2 = sl[k][tx];
      int i2 = si[k][tx];
      if (m2 > m)       { l = l * expf(m - m2) + l2; m = m2; idx = i2; }
      else if (m2 == m) { l += l2; idx = min(idx, i2); }
      else              { l += l2 * expf(m2 - m); }
    }
    size_t p = (size_t)(b * 8 + blockIdx.y) * TT + t;
    mPart[p] = m; lPart[p] = l; iPart[p] = idx;
  }
}

// ---------------- K2b: combine chunk partials ----------------
__global__ __launch_bounds__(256) void stats_final(const float* __restrict__ mPart,
                                                   const float* __restrict__ lPart,
                                                   const int* __restrict__ iPart,
                                                   float* __restrict__ mArr,
                                                   float* __restrict__ rlArr,
                                                   float* __restrict__ outMax) {
  int col = blockIdx.x * 256 + threadIdx.x;  // 0..8191  (b*T + t)
  int b = col >> 10, t = col & 1023;
  float m = -FLT_MAX, l = 0.f;
  int idx = 0;
#pragma unroll
  for (int c = 0; c < 8; ++c) {
    size_t p = (size_t)(b * 8 + c) * TT + t;
    float m2 = mPart[p], l2 = lPart[p];
    int i2 = iPart[p];
    if (m2 > m)       { l = l * expf(m - m2) + l2; m = m2; idx = i2; }
    else if (m2 == m) { l += l2; idx = min(idx, i2); }
    else              { l += l2 * expf(m2 - m); }
  }
  mArr[col] = m;
  rlArr[col] = 1.0f / l;
  outMax[col] = (float)idx;   // buffer is read back as float32
}

// ---------------- K3: A = exp(S - m) / l  (in place, float4) ----------------
__global__ __launch_bounds__(256) void normalize(float* __restrict__ A,
                                                 const float* __restrict__ mArr,
                                                 const float* __restrict__ rlArr) {
  int g = blockIdx.x * 256 + threadIdx.x;  // 0..8388607
  float4 s = ((const float4*)A)[g];
  int e = g * 4;
  int t0 = e & 1023;
  int row = e >> 10;   // b*N + n
  int b = row >> 12;
  int cb = (b << 10) + t0;
  float4 r;
  r.x = expf(s.x - mArr[cb + 0]) * rlArr[cb + 0];
  r.y = expf(s.y - mArr[cb + 1]) * rlArr[cb + 1];
  r.z = expf(s.z - mArr[cb + 2]) * rlArr[cb + 2];
  r.w = expf(s.w - mArr[cb + 3]) * rlArr[cb + 3];
  ((float4*)A)[g] = r;
}

// ---------------- K4: R = V @ A  → top half of R_ ----------------
// tile 64(d) x 128(t), block 256 (16x16), micro 4x8, k-chunk 16
__global__ __launch_bounds__(256) void gemm_out(const float* __restrict__ Vp,
                                                const float* __restrict__ A,
                                                float* __restrict__ Rout) {
  const int b = blockIdx.z;
  const int m0 = blockIdx.y * 64;
  const int t0 = blockIdx.x * 128;
  const int tid = threadIdx.x;
  const int tx = tid & 15, ty = tid >> 4;

  __shared__ float Vt[16][68];    // [k][m], padded
  __shared__ float At[16][128];   // [k][t]

  float acc[4][8];
#pragma unroll
  for (int i = 0; i < 4; ++i)
#pragma unroll
    for (int j = 0; j < 8; ++j) acc[i][j] = 0.f;

  const float* Vbase = Vp + (size_t)b * DD * NN;
  const float* Abase = A + (size_t)b * NN * TT;

  const int vmm = tid >> 2;        // 0..63
  const int vkk = (tid & 3) * 4;   // 0,4,8,12
  const int akk = tid >> 5;        // 0..7
  const int att = (tid * 4) & 127;

  for (int nn0 = 0; nn0 < NN; nn0 += 16) {
    float4 vv = *(const float4*)(Vbase + (size_t)(m0 + vmm) * NN + nn0 + vkk);
    float4 a0 = *(const float4*)(Abase + (size_t)(nn0 + akk) * TT + t0 + att);
    float4 a1 = *(const float4*)(Abase + (size_t)(nn0 + akk + 8) * TT + t0 + att);
    __syncthreads();
    Vt[vkk + 0][vmm] = vv.x;
    Vt[vkk + 1][vmm] = vv.y;
    Vt[vkk + 2][vmm] = vv.z;
    Vt[vkk + 3][vmm] = vv.w;
    *(float4*)&At[akk][att] = a0;
    *(float4*)&At[akk + 8][att] = a1;
    __syncthreads();
#pragma unroll
    for (int kk = 0; kk < 16; ++kk) {
      float4 a4 = *(float4*)&Vt[kk][ty * 4];
      float4 b0 = *(float4*)&At[kk][tx * 4];
      float4 b1 = *(float4*)&At[kk][64 + tx * 4];
      float av[4] = {a4.x, a4.y, a4.z, a4.w};
      float bv[8] = {b0.x, b0.y, b0.z, b0.w, b1.x, b1.y, b1.z, b1.w};
#pragma unroll
      for (int i = 0; i < 4; ++i)
#pragma unroll
        for (int j = 0; j < 8; ++j) acc[i][j] += av[i] * bv[j];
    }
  }

#pragma unroll
  for (int i = 0; i < 4; ++i) {
    int r = m0 + ty * 4 + i;
    float* dst = Rout + (size_t)b * (2 * DD) * TT + (size_t)r * TT + t0;
    float4 v0 = make_float4(acc[i][0], acc[i][1], acc[i][2], acc[i][3]);
    float4 v1 = make_float4(acc[i][4], acc[i][5], acc[i][6], acc[i][7]);
    *(float4*)(dst + tx * 4) = v0;
    *(float4*)(dst + 64 + tx * 4) = v1;
  }
}

// ---------------- K5: copy Q into bottom half of R_ ----------------
__global__ __launch_bounds__(256) void qcopy(const float* __restrict__ Qp,
                                             float* __restrict__ out) {
  int g = blockIdx.x * 256 + threadIdx.x;  // 0..524287
  int e = g * 4;
  int t0 = e & 1023;
  int row = e >> 10;        // b*256 + dd
  int dd = row & 255, b = row >> 8;
  float4 v = ((const float4*)Qp)[g];
  *(float4*)(out + (size_t)b * 512 * TT + (size_t)(256 + dd) * TT + t0) = v;
}

extern "C" void kernel_launch(void* const* d_in, const int* in_sizes, int n_in,
                              void* d_out, int out_size, void* d_ws, size_t ws_size,
                              hipStream_t stream) {
  const float* Kp = (const float*)d_in[0];
  const float* Vp = (const float*)d_in[1];
  const float* Qp = (const float*)d_in[2];
  float* out = (float*)d_out;
  float* R_ = out;                       // 8*512*1024 = 4194304
  float* A = out + 4194304;              // 8*4096*1024 = 33554432
  float* outMax = out + 4194304 + 33554432;  // 8192

  float* wsf = (float*)d_ws;
  float* mPart = wsf;                    // 65536
  float* lPart = wsf + 65536;            // 65536
  int* iPart = (int*)(wsf + 131072);     // 65536
  float* mArr = wsf + 196608;            // 8192
  float* rlArr = wsf + 204800;           // 8192

  // S (raw scaled scores) lives in the A output region until normalize().
  gemm_scores<<<dim3(TT / 128, NN / 128, BB), 256, 0, stream>>>(Kp, Qp, A);
  stats_partial<<<dim3(TT / 64, NN / 512, BB), 256, 0, stream>>>(A, mPart, lPart, iPart);
  stats_final<<<dim3(32), 256, 0, stream>>>(mPart, lPart, iPart, mArr, rlArr, outMax);
  normalize<<<dim3((BB * NN * TT / 4) / 256), 256, 0, stream>>>(A, mArr, rlArr);
  gemm_out<<<dim3(TT / 128, DD / 64, BB), 256, 0, stream>>>(Vp, A, R_);
  qcopy<<<dim3((BB * DD * TT / 4) / 256), 256, 0, stream>>>(Qp, R_);
}

// Round 2
// 451.845 us; speedup vs baseline: 1.7989x; 1.7989x over previous
//
#include <hip/hip_runtime.h>
#include <cfloat>

#define BB 8
#define DD 256
#define NN 4096
#define TT 1024
constexpr float SCALE = 0.0625f;   // 1/sqrt(256)

typedef __attribute__((ext_vector_type(8))) short bf16x8;
typedef __attribute__((ext_vector_type(4))) float f32x4;
typedef __attribute__((ext_vector_type(8))) unsigned short u16x8;

__device__ inline unsigned short f2bf(float x) {
  union { float f; unsigned u; } v; v.f = x;
  unsigned r = v.u + 0x7fff + ((v.u >> 16) & 1);
  return (unsigned short)(r >> 16);
}
__device__ inline float bf2f(unsigned short h) {
  union { unsigned u; float f; } v; v.u = ((unsigned)h) << 16;
  return v.f;
}

// async global->LDS, 16B per lane; lds base must be wave-uniform (lane i writes base + i*16)
__device__ inline void glds16(const unsigned short* g, const short* lbase) {
  __builtin_amdgcn_global_load_lds((const __attribute__((address_space(1))) unsigned int*)g,
                                   (__attribute__((address_space(3))) unsigned int*)lbase,
                                   16, 0, 0);
}

// ws byte offsets (fast path)
#define STATS_BYTES   (1u << 20)
#define KT_HI_OFF     (1048576u)
#define KT_LO_OFF     (17825792u)
#define QT_HI_OFF     (34603008u)
#define QT_LO_OFF     (38797312u)
#define VH_OFF        (42991616u)
#define WS_NEED       (59768832ull)

// ---------------- convert+transpose+split: src (B,256,C) f32 -> dst (B,C,256) bf16 hi/lo ------
__global__ __launch_bounds__(256) void convert_t(const float* __restrict__ src,
                                                 unsigned short* __restrict__ dhi,
                                                 unsigned short* __restrict__ dlo,
                                                 int C) {
  __shared__ float tile[64][65];
  const int b = blockIdx.z, c0 = blockIdx.x * 64, d0 = blockIdx.y * 64;
  const int tid = threadIdx.x;
  const float* s = src + ((size_t)b * DD + d0) * C + c0;
  const int r = tid >> 4, cg = (tid & 15) * 4;
#pragma unroll
  for (int it = 0; it < 4; ++it) {
    float4 v = *(const float4*)(s + (size_t)(r + it * 16) * C + cg);
    tile[r + it * 16][cg + 0] = v.x; tile[r + it * 16][cg + 1] = v.y;
    tile[r + it * 16][cg + 2] = v.z; tile[r + it * 16][cg + 3] = v.w;
  }
  __syncthreads();
  const int cl = tid >> 2, dg = (tid & 3) * 16;
  unsigned short hi[16], lo[16];
#pragma unroll
  for (int j = 0; j < 16; ++j) {
    float x = tile[dg + j][cl];
    unsigned short h = f2bf(x);
    hi[j] = h;
    lo[j] = f2bf(x - bf2f(h));
  }
  size_t off = ((size_t)b * C + c0 + cl) * DD + d0 + dg;
  *(u16x8*)(dhi + off) = *(u16x8*)&hi[0];
  *(u16x8*)(dhi + off + 8) = *(u16x8*)&hi[8];
  *(u16x8*)(dlo + off) = *(u16x8*)&lo[0];
  *(u16x8*)(dlo + off + 8) = *(u16x8*)&lo[8];
}

// ---------------- convert V (no transpose, hi only) ----------------
__global__ __launch_bounds__(256) void convert_v(const float* __restrict__ src,
                                                 unsigned short* __restrict__ dhi) {
  size_t g = (size_t)blockIdx.x * 256 + threadIdx.x;
  float4 v = ((const float4*)src)[g];
  unsigned short h[4] = {f2bf(v.x), f2bf(v.y), f2bf(v.z), f2bf(v.w)};
  *(ushort4*)(dhi + g * 4) = *(ushort4*)h;
}

// ---------------- K1: S = scale * K^T Q via split-bf16 MFMA ----------------
// tile 128n x 128t, 4 waves, each 64x64; k=d=256, chunk 32
__global__ __launch_bounds__(256) void gemm_scores_mfma(const unsigned short* __restrict__ KtHi,
                                                        const unsigned short* __restrict__ KtLo,
                                                        const unsigned short* __restrict__ QtHi,
                                                        const unsigned short* __restrict__ QtLo,
                                                        float* __restrict__ S) {
  __shared__ short sAhi[128 * 32];
  __shared__ short sAlo[128 * 32];
  __shared__ short sBhi[128 * 32];
  __shared__ short sBlo[128 * 32];

  const int b = blockIdx.z;
  const int n0 = blockIdx.y * 128;
  const int t0 = blockIdx.x * 128;
  const int tid = threadIdx.x;
  const int lane = tid & 63, w = tid >> 6;
  const int nh = (w & 1) * 64, th = (w >> 1) * 64;
  const int fr = lane & 15, fk = (lane >> 4) * 8;

  const unsigned short* aHi = KtHi + ((size_t)b * NN + n0) * DD;
  const unsigned short* aLo = KtLo + ((size_t)b * NN + n0) * DD;
  const unsigned short* bHi = QtHi + ((size_t)b * TT + t0) * DD;
  const unsigned short* bLo = QtLo + ((size_t)b * TT + t0) * DD;

  f32x4 acc[4][4];
#pragma unroll
  for (int i = 0; i < 4; ++i)
#pragma unroll
    for (int j = 0; j < 4; ++j) acc[i][j] = (f32x4){0.f, 0.f, 0.f, 0.f};

  // staging chunk indices for this thread: p = w*128 + c*64 + lane, c in {0,1}
  const int p0 = w * 128 + lane;           // c=0
  const int p1 = p0 + 64;                  // c=1
  const int r0 = p0 >> 2, k0 = (p0 & 3) * 8;
  const int r1 = p1 >> 2, k1 = (p1 & 3) * 8;
  const int l0 = p0 * 8 - lane * 8;        // wave-uniform LDS short-offset base (p0 - lane = w*128)
  const int l1 = l0 + 64 * 8;

  for (int kk = 0; kk < DD; kk += 32) {
    glds16(aHi + (size_t)r0 * DD + kk + k0, sAhi + l0);
    glds16(aHi + (size_t)r1 * DD + kk + k1, sAhi + l1);
    glds16(aLo + (size_t)r0 * DD + kk + k0, sAlo + l0);
    glds16(aLo + (size_t)r1 * DD + kk + k1, sAlo + l1);
    glds16(bHi + (size_t)r0 * DD + kk + k0, sBhi + l0);
    glds16(bHi + (size_t)r1 * DD + kk + k1, sBhi + l1);
    glds16(bLo + (size_t)r0 * DD + kk + k0, sBlo + l0);
    glds16(bLo + (size_t)r1 * DD + kk + k1, sBlo + l1);
    __syncthreads();

    bf16x8 bh[4], bl[4];
#pragma unroll
    for (int tb = 0; tb < 4; ++tb) {
      int r = th + tb * 16 + fr;
      bh[tb] = *(const bf16x8*)&sBhi[r * 32 + fk];
      bl[tb] = *(const bf16x8*)&sBlo[r * 32 + fk];
    }
#pragma unroll
    for (int mb = 0; mb < 4; ++mb) {
      int r = nh + mb * 16 + fr;
      bf16x8 ah = *(const bf16x8*)&sAhi[r * 32 + fk];
      bf16x8 al = *(const bf16x8*)&sAlo[r * 32 + fk];
#pragma unroll
      for (int tb = 0; tb < 4; ++tb) {
        acc[mb][tb] = __builtin_amdgcn_mfma_f32_16x16x32_bf16(ah, bh[tb], acc[mb][tb], 0, 0, 0);
        acc[mb][tb] = __builtin_amdgcn_mfma_f32_16x16x32_bf16(ah, bl[tb], acc[mb][tb], 0, 0, 0);
        acc[mb][tb] = __builtin_amdgcn_mfma_f32_16x16x32_bf16(al, bh[tb], acc[mb][tb], 0, 0, 0);
      }
    }
    __syncthreads();
  }

  // epilogue: C/D layout col=lane&15, row=(lane>>4)*4+reg  [m89-verified]
#pragma unroll
  for (int mb = 0; mb < 4; ++mb)
#pragma unroll
    for (int tb = 0; tb < 4; ++tb) {
      int t = t0 + th + tb * 16 + fr;
#pragma unroll
      for (int r = 0; r < 4; ++r) {
        int n = n0 + nh + mb * 16 + (lane >> 4) * 4 + r;
        S[((size_t)b * NN + n) * TT + t] = acc[mb][tb][r] * SCALE;
      }
    }
}

// ---------------- K2a: partial softmax stats over 512-key chunks (fp32 exact) ----------------
__global__ __launch_bounds__(256) void stats_partial(const float* __restrict__ S,
                                                     float* __restrict__ mPart,
                                                     float* __restrict__ lPart,
                                                     int* __restrict__ iPart) {
  const int tid = threadIdx.x;
  const int tx = tid & 63, ty = tid >> 6;
  const int b = blockIdx.z;
  const int t = blockIdx.x * 64 + tx;
  const int nbase = blockIdx.y * 512;

  float m = -FLT_MAX;
  float l = 0.f;
  int idx = 0;
  const float* col = S + (size_t)b * NN * TT + t;
  for (int n = nbase + ty; n < nbase + 512; n += 4) {
    float s = col[(size_t)n * TT];
    if (s > m) { l = l * __expf(m - s) + 1.0f; m = s; idx = n; }
    else        l += __expf(s - m);
  }
  __shared__ float sm[4][64], sl[4][64];
  __shared__ int si[4][64];
  sm[ty][tx] = m; sl[ty][tx] = l; si[ty][tx] = idx;
  __syncthreads();
  if (ty == 0) {
#pragma unroll
    for (int k = 1; k < 4; ++k) {
      float m2 = sm[k][tx], l2 = sl[k][tx];
      int i2 = si[k][tx];
      if (m2 > m)       { l = l * __expf(m - m2) + l2; m = m2; idx = i2; }
      else if (m2 == m) { l += l2; idx = min(idx, i2); }
      else              { l += l2 * __expf(m2 - m); }
    }
    size_t p = (size_t)(b * 8 + blockIdx.y) * TT + t;
    mPart[p] = m; lPart[p] = l; iPart[p] = idx;
  }
}

// ---------------- K2b: combine chunk partials ----------------
__global__ __launch_bounds__(256) void stats_final(const float* __restrict__ mPart,
                                                   const float* __restrict__ lPart,
                                                   const int* __restrict__ iPart,
                                                   float* __restrict__ mArr,
                                                   float* __restrict__ rlArr,
                                                   float* __restrict__ outMax) {
  int col = blockIdx.x * 256 + threadIdx.x;  // b*T + t
  int b = col >> 10, t = col & 1023;
  float m = -FLT_MAX, l = 0.f;
  int idx = 0;
#pragma unroll
  for (int c = 0; c < 8; ++c) {
    size_t p = (size_t)(b * 8 + c) * TT + t;
    float m2 = mPart[p], l2 = lPart[p];
    int i2 = iPart[p];
    if (m2 > m)       { l = l * __expf(m - m2) + l2; m = m2; idx = i2; }
    else if (m2 == m) { l += l2; idx = min(idx, i2); }
    else              { l += l2 * __expf(m2 - m); }
  }
  mArr[col] = m;
  rlArr[col] = 1.0f / l;
  outMax[col] = (float)idx;
}

// ---------------- K3: A = exp(S - m) / l  (in place, float4) ----------------
__global__ __launch_bounds__(256) void normalize(float* __restrict__ A,
                                                 const float* __restrict__ mArr,
                                                 const float* __restrict__ rlArr) {
  int g = blockIdx.x * 256 + threadIdx.x;
  float4 s = ((const float4*)A)[g];
  int e = g * 4;
  int t0 = e & 1023;
  int row = e >> 10;   // b*N + n
  int b = row >> 12;
  int cb = (b << 10) + t0;
  float4 r;
  r.x = __expf(s.x - mArr[cb + 0]) * rlArr[cb + 0];
  r.y = __expf(s.y - mArr[cb + 1]) * rlArr[cb + 1];
  r.z = __expf(s.z - mArr[cb + 2]) * rlArr[cb + 2];
  r.w = __expf(s.w - mArr[cb + 3]) * rlArr[cb + 3];
  ((float4*)A)[g] = r;
}

// ---------------- K4: R = V @ A via bf16 MFMA ----------------
// block 512 thr (8 waves), tile d=256(full) x t=32; wave w covers d in [w*32, w*32+32)
__global__ __launch_bounds__(512) void gemm_out_mfma(const unsigned short* __restrict__ Vh,
                                                     const float* __restrict__ A,
                                                     float* __restrict__ Rout) {
  __shared__ short sV[256 * 32];    // [d][k] bf16, 16 KB
  __shared__ short sBt[32 * 40];    // [t][k] bf16, padded rows (40 shorts)

  const int b = blockIdx.y;
  const int t0 = blockIdx.x * 32;
  const int tid = threadIdx.x;
  const int lane = tid & 63, w = tid >> 6;
  const int fr = lane & 15, fk = (lane >> 4) * 8;

  f32x4 acc[2][2];
#pragma unroll
  for (int i = 0; i < 2; ++i)
#pragma unroll
    for (int j = 0; j < 2; ++j) acc[i][j] = (f32x4){0.f, 0.f, 0.f, 0.f};

  const unsigned short* Vb = Vh + (size_t)b * DD * NN;
  const float* Ab = A + (size_t)b * NN * TT + t0;

  // V staging chunks: p = it*512 + w*64 + lane -> d = p>>2, kc = (p&3)*8
  const int pa = w * 64 + lane;
  const int pb = pa + 512;
  const int da = pa >> 2, ka = (pa & 3) * 8;
  const int db = pb >> 2, kb = (pb & 3) * 8;
  const int la = (w * 64) * 8;           // wave-uniform LDS short offsets
  const int lb = la + 512 * 8;

  // sBt writer mapping (first 256 threads): n = tid>>3, t-group = tid&7
  const int wn = tid >> 3, wtg = tid & 7;

  for (int nn = 0; nn < NN; nn += 32) {
    glds16(Vb + (size_t)da * NN + nn + ka, sV + la);
    glds16(Vb + (size_t)db * NN + nn + kb, sV + lb);
    if (tid < 256) {
      float4 v = *(const float4*)(Ab + (size_t)(nn + wn) * TT + wtg * 4);
      sBt[(wtg * 4 + 0) * 40 + wn] = (short)f2bf(v.x);
      sBt[(wtg * 4 + 1) * 40 + wn] = (short)f2bf(v.y);
      sBt[(wtg * 4 + 2) * 40 + wn] = (short)f2bf(v.z);
      sBt[(wtg * 4 + 3) * 40 + wn] = (short)f2bf(v.w);
    }
    __syncthreads();

    bf16x8 bf0 = *(const bf16x8*)&sBt[(0 * 16 + fr) * 40 + fk];
    bf16x8 bf1 = *(const bf16x8*)&sBt[(1 * 16 + fr) * 40 + fk];
#pragma unroll
    for (int mb = 0; mb < 2; ++mb) {
      int d = w * 32 + mb * 16 + fr;
      bf16x8 af = *(const bf16x8*)&sV[d * 32 + fk];
      acc[mb][0] = __builtin_amdgcn_mfma_f32_16x16x32_bf16(af, bf0, acc[mb][0], 0, 0, 0);
      acc[mb][1] = __builtin_amdgcn_mfma_f32_16x16x32_bf16(af, bf1, acc[mb][1], 0, 0, 0);
    }
    __syncthreads();
  }

#pragma unroll
  for (int mb = 0; mb < 2; ++mb)
#pragma unroll
    for (int tb = 0; tb < 2; ++tb) {
      int t = t0 + tb * 16 + fr;
#pragma unroll
      for (int r = 0; r < 4; ++r) {
        int d = w * 32 + mb * 16 + (lane >> 4) * 4 + r;
        Rout[((size_t)b * 512 + d) * TT + t] = acc[mb][tb][r];
      }
    }
}

// ---------------- K5: copy Q into bottom half of R_ ----------------
__global__ __launch_bounds__(256) void qcopy(const float* __restrict__ Qp,
                                             float* __restrict__ out) {
  int g = blockIdx.x * 256 + threadIdx.x;
  int e = g * 4;
  int t0 = e & 1023;
  int row = e >> 10;        // b*256 + dd
  int dd = row & 255, b = row >> 8;
  float4 v = ((const float4*)Qp)[g];
  *(float4*)(out + (size_t)b * 512 * TT + (size_t)(256 + dd) * TT + t0) = v;
}

// =================== fp32 fallback GEMMs (used only if ws too small) ===================
__global__ __launch_bounds__(256) void gemm_scores_fp32(const float* __restrict__ Kp,
                                                        const float* __restrict__ Qp,
                                                        float* __restrict__ S) {
  const int b = blockIdx.z;
  const int n0 = blockIdx.y * 128;
  const int t0 = blockIdx.x * 128;
  const int tid = threadIdx.x;
  const int tx = tid & 15, ty = tid >> 4;
  __shared__ float Kt[8][128];
  __shared__ float Qt[8][128];
  float acc[8][8];
#pragma unroll
  for (int i = 0; i < 8; ++i)
#pragma unroll
    for (int j = 0; j < 8; ++j) acc[i][j] = 0.f;
  const int lin = tid * 4;
  const int lkk = lin >> 7, lcol = lin & 127;
  const float* Kbase = Kp + (size_t)b * DD * NN;
  const float* Qbase = Qp + (size_t)b * DD * TT;
  for (int dd0 = 0; dd0 < DD; dd0 += 8) {
    float4 kv = *(const float4*)(Kbase + (size_t)(dd0 + lkk) * NN + n0 + lcol);
    float4 qv = *(const float4*)(Qbase + (size_t)(dd0 + lkk) * TT + t0 + lcol);
    __syncthreads();
    *(float4*)&Kt[lkk][lcol] = kv;
    *(float4*)&Qt[lkk][lcol] = qv;
    __syncthreads();
#pragma unroll
    for (int kk = 0; kk < 8; ++kk) {
      float4 a0 = *(float4*)&Kt[kk][ty * 4];
      float4 a1 = *(float4*)&Kt[kk][64 + ty * 4];
      float4 b0 = *(float4*)&Qt[kk][tx * 4];
      float4 b1 = *(float4*)&Qt[kk][64 + tx * 4];
      float av[8] = {a0.x, a0.y, a0.z, a0.w, a1.x, a1.y, a1.z, a1.w};
      float bv[8] = {b0.x, b0.y, b0.z, b0.w, b1.x, b1.y, b1.z, b1.w};
#pragma unroll
      for (int i = 0; i < 8; ++i)
#pragma unroll
        for (int j = 0; j < 8; ++j) acc[i][j] += av[i] * bv[j];
    }
  }
#pragma unroll
  for (int i = 0; i < 8; ++i) {
    int r = n0 + ((i < 4) ? (ty * 4 + i) : (64 + ty * 4 + i - 4));
    float* dst = S + ((size_t)b * NN + r) * TT + t0;
    *(float4*)(dst + tx * 4) = make_float4(acc[i][0] * SCALE, acc[i][1] * SCALE, acc[i][2] * SCALE, acc[i][3] * SCALE);
    *(float4*)(dst + 64 + tx * 4) = make_float4(acc[i][4] * SCALE, acc[i][5] * SCALE, acc[i][6] * SCALE, acc[i][7] * SCALE);
  }
}

__global__ __launch_bounds__(256) void gemm_out_fp32(const float* __restrict__ Vp,
                                                     const float* __restrict__ A,
                                                     float* __restrict__ Rout) {
  const int b = blockIdx.z;
  const int m0 = blockIdx.y * 64;
  const int t0 = blockIdx.x * 128;
  const int tid = threadIdx.x;
  const int tx = tid & 15, ty = tid >> 4;
  __shared__ float Vt[16][68];
  __shared__ float At[16][128];
  float acc[4][8];
#pragma unroll
  for (int i = 0; i < 4; ++i)
#pragma unroll
    for (int j = 0; j < 8; ++j) acc[i][j] = 0.f;
  const float* Vbase = Vp + (size_t)b * DD * NN;
  const float* Abase = A + (size_t)b * NN * TT;
  const int vmm = tid >> 2, vkk = (tid & 3) * 4;
  const int akk = tid >> 5, att = (tid * 4) & 127;
  for (int nn0 = 0; nn0 < NN; nn0 += 16) {
    float4 vv = *(const float4*)(Vbase + (size_t)(m0 + vmm) * NN + nn0 + vkk);
    float4 a0 = *(const float4*)(Abase + (size_t)(nn0 + akk) * TT + t0 + att);
    float4 a1 = *(const float4*)(Abase + (size_t)(nn0 + akk + 8) * TT + t0 + att);
    __syncthreads();
    Vt[vkk + 0][vmm] = vv.x; Vt[vkk + 1][vmm] = vv.y;
    Vt[vkk + 2][vmm] = vv.z; Vt[vkk + 3][vmm] = vv.w;
    *(float4*)&At[akk][att] = a0;
    *(float4*)&At[akk + 8][att] = a1;
    __syncthreads();
#pragma unroll
    for (int kk = 0; kk < 16; ++kk) {
      float4 a4 = *(float4*)&Vt[kk][ty * 4];
      float4 b0 = *(float4*)&At[kk][tx * 4];
      float4 b1 = *(float4*)&At[kk][64 + tx * 4];
      float av[4] = {a4.x, a4.y, a4.z, a4.w};
      float bv[8] = {b0.x, b0.y, b0.z, b0.w, b1.x, b1.y, b1.z, b1.w};
#pragma unroll
      for (int i = 0; i < 4; ++i)
#pragma unroll
        for (int j = 0; j < 8; ++j) acc[i][j] += av[i] * bv[j];
    }
  }
#pragma unroll
  for (int i = 0; i < 4; ++i) {
    int r = m0 + ty * 4 + i;
    float* dst = Rout + (size_t)b * (2 * DD) * TT + (size_t)r * TT + t0;
    *(float4*)(dst + tx * 4) = make_float4(acc[i][0], acc[i][1], acc[i][2], acc[i][3]);
    *(float4*)(dst + 64 + tx * 4) = make_float4(acc[i][4], acc[i][5], acc[i][6], acc[i][7]);
  }
}

extern "C" void kernel_launch(void* const* d_in, const int* in_sizes, int n_in,
                              void* d_out, int out_size, void* d_ws, size_t ws_size,
                              hipStream_t stream) {
  const float* Kp = (const float*)d_in[0];
  const float* Vp = (const float*)d_in[1];
  const float* Qp = (const float*)d_in[2];
  float* out = (float*)d_out;
  float* R_ = out;                           // 8*512*1024
  float* A = out + 4194304;                  // 8*4096*1024  (holds raw S, then A)
  float* outMax = out + 4194304 + 33554432;  // 8192

  char* wsb = (char*)d_ws;
  float* mPart = (float*)wsb;                      // 65536 f
  float* lPart = (float*)(wsb + 262144);           // 65536 f
  int*   iPart = (int*)(wsb + 524288);             // 65536 i
  float* mArr  = (float*)(wsb + 786432);           // 8192 f
  float* rlArr = (float*)(wsb + 819200);           // 8192 f

  const bool fast = (ws_size >= WS_NEED);

  if (fast) {
    unsigned short* KtHi = (unsigned short*)(wsb + KT_HI_OFF);
    unsigned short* KtLo = (unsigned short*)(wsb + KT_LO_OFF);
    unsigned short* QtHi = (unsigned short*)(wsb + QT_HI_OFF);
    unsigned short* QtLo = (unsigned short*)(wsb + QT_LO_OFF);
    unsigned short* Vh   = (unsigned short*)(wsb + VH_OFF);

    convert_t<<<dim3(NN / 64, 4, BB), 256, 0, stream>>>(Kp, KtHi, KtLo, NN);
    convert_t<<<dim3(TT / 64, 4, BB), 256, 0, stream>>>(Qp, QtHi, QtLo, TT);
    convert_v<<<dim3((BB * DD * NN / 4) / 256), 256, 0, stream>>>(Vp, Vh);
    gemm_scores_mfma<<<dim3(TT / 128, NN / 128, BB), 256, 0, stream>>>(KtHi, KtLo, QtHi, QtLo, A);
    stats_partial<<<dim3(TT / 64, NN / 512, BB), 256, 0, stream>>>(A, mPart, lPart, iPart);
    stats_final<<<dim3(32), 256, 0, stream>>>(mPart, lPart, iPart, mArr, rlArr, outMax);
    normalize<<<dim3((BB * NN * TT / 4) / 256), 256, 0, stream>>>(A, mArr, rlArr);
    gemm_out_mfma<<<dim3(TT / 32, BB), 512, 0, stream>>>(Vh, A, R_);
    qcopy<<<dim3((BB * DD * TT / 4) / 256), 256, 0, stream>>>(Qp, R_);
  } else {
    gemm_scores_fp32<<<dim3(TT / 128, NN / 128, BB), 256, 0, stream>>>(Kp, Qp, A);
    stats_partial<<<dim3(TT / 64, NN / 512, BB), 256, 0, stream>>>(A, mPart, lPart, iPart);
    stats_final<<<dim3(32), 256, 0, stream>>>(mPart, lPart, iPart, mArr, rlArr, outMax);
    normalize<<<dim3((BB * NN * TT / 4) / 256), 256, 0, stream>>>(A, mArr, rlArr);
    gemm_out_fp32<<<dim3(TT / 128, DD / 64, BB), 256, 0, stream>>>(Vp, A, R_);
    qcopy<<<dim3((BB * DD * TT / 4) / 256), 256, 0, stream>>>(Qp, R_);
  }
}

// Round 3
// 418.450 us; speedup vs baseline: 1.9425x; 1.0798x over previous
//
#include <hip/hip_runtime.h>
#include <cfloat>

#define BB 8
#define DD 256
#define NN 4096
#define TT 1024
constexpr float SCALE = 0.0625f;   // 1/sqrt(256)

typedef __attribute__((ext_vector_type(8))) short bf16x8;
typedef __attribute__((ext_vector_type(4))) float f32x4;
typedef __attribute__((ext_vector_type(8))) unsigned short u16x8;

__device__ inline unsigned short f2bf(float x) {
  union { float f; unsigned u; } v; v.f = x;
  unsigned r = v.u + 0x7fff + ((v.u >> 16) & 1);
  return (unsigned short)(r >> 16);
}
__device__ inline float bf2f(unsigned short h) {
  union { unsigned u; float f; } v; v.u = ((unsigned)h) << 16;
  return v.f;
}

__device__ inline void glds16(const unsigned short* g, const short* lbase) {
  __builtin_amdgcn_global_load_lds((const __attribute__((address_space(1))) unsigned int*)g,
                                   (__attribute__((address_space(3))) unsigned int*)lbase,
                                   16, 0, 0);
}

// ---- ws layout (bytes) ----
#define MPART_OFF 0u                      // 8*32*1024 f = 1 MB
#define LPART_OFF (1u << 20)
#define IPART_OFF (2u << 20)
#define MARR_OFF  (3u << 20)
#define RLARR_OFF ((3u << 20) + 32768u)
#define CONV_OFF  (4u << 20)
#define KT_HI_OFF (CONV_OFF)
#define KT_LO_OFF (CONV_OFF + 16777216u)
#define QT_HI_OFF (CONV_OFF + 33554432u)
#define QT_LO_OFF (CONV_OFF + 37748736u)
#define VH_OFF    (CONV_OFF + 41943040u)
#define RPART_OFF (CONV_OFF)              // aliases Kt hi/lo (dead after gemm_scores)
#define WS_NEED   (62914560ull)

// ---------------- convert+transpose+split ----------------
__global__ __launch_bounds__(256) void convert_t(const float* __restrict__ src,
                                                 unsigned short* __restrict__ dhi,
                                                 unsigned short* __restrict__ dlo,
                                                 int C) {
  __shared__ float tile[64][65];
  const int b = blockIdx.z, c0 = blockIdx.x * 64, d0 = blockIdx.y * 64;
  const int tid = threadIdx.x;
  const float* s = src + ((size_t)b * DD + d0) * C + c0;
  const int r = tid >> 4, cg = (tid & 15) * 4;
#pragma unroll
  for (int it = 0; it < 4; ++it) {
    float4 v = *(const float4*)(s + (size_t)(r + it * 16) * C + cg);
    tile[r + it * 16][cg + 0] = v.x; tile[r + it * 16][cg + 1] = v.y;
    tile[r + it * 16][cg + 2] = v.z; tile[r + it * 16][cg + 3] = v.w;
  }
  __syncthreads();
  const int cl = tid >> 2, dg = (tid & 3) * 16;
  unsigned short hi[16], lo[16];
#pragma unroll
  for (int j = 0; j < 16; ++j) {
    float x = tile[dg + j][cl];
    unsigned short h = f2bf(x);
    hi[j] = h;
    lo[j] = f2bf(x - bf2f(h));
  }
  size_t off = ((size_t)b * C + c0 + cl) * DD + d0 + dg;
  *(u16x8*)(dhi + off) = *(u16x8*)&hi[0];
  *(u16x8*)(dhi + off + 8) = *(u16x8*)&hi[8];
  *(u16x8*)(dlo + off) = *(u16x8*)&lo[0];
  *(u16x8*)(dlo + off + 8) = *(u16x8*)&lo[8];
}

__global__ __launch_bounds__(256) void convert_v(const float* __restrict__ src,
                                                 unsigned short* __restrict__ dhi) {
  size_t g = (size_t)blockIdx.x * 256 + threadIdx.x;
  float4 v = ((const float4*)src)[g];
  unsigned short h[4] = {f2bf(v.x), f2bf(v.y), f2bf(v.z), f2bf(v.w)};
  *(ushort4*)(dhi + g * 4) = *(ushort4*)h;
}

// ---------------- K1: S = scale*K^T Q (split-bf16 MFMA) + per-block softmax stats ----------------
// tile 128n x 128t, 4 waves; LDS staged as [kc][row][8] (conflict-free)
__global__ __launch_bounds__(256) void gemm_scores_mfma(const unsigned short* __restrict__ KtHi,
                                                        const unsigned short* __restrict__ KtLo,
                                                        const unsigned short* __restrict__ QtHi,
                                                        const unsigned short* __restrict__ QtLo,
                                                        float* __restrict__ S,
                                                        float* __restrict__ mPart,
                                                        float* __restrict__ lPart,
                                                        int* __restrict__ iPart) {
  __shared__ short sAhi[128 * 32];
  __shared__ short sAlo[128 * 32];
  __shared__ short sBhi[128 * 32];
  __shared__ short sBlo[128 * 32];
  __shared__ float sm[256], sl[256];
  __shared__ int si[256];

  const int b = blockIdx.z;
  const int n0 = blockIdx.y * 128;
  const int t0 = blockIdx.x * 128;
  const int tid = threadIdx.x;
  const int lane = tid & 63, w = tid >> 6;
  const int nh = (w & 1) * 64, th = (w >> 1) * 64;
  const int fr = lane & 15, q = lane >> 4;

  const unsigned short* aHi = KtHi + ((size_t)b * NN + n0) * DD;
  const unsigned short* aLo = KtLo + ((size_t)b * NN + n0) * DD;
  const unsigned short* bHi = QtHi + ((size_t)b * TT + t0) * DD;
  const unsigned short* bLo = QtLo + ((size_t)b * TT + t0) * DD;

  f32x4 acc[4][4];
#pragma unroll
  for (int i = 0; i < 4; ++i)
#pragma unroll
    for (int j = 0; j < 4; ++j) acc[i][j] = (f32x4){0.f, 0.f, 0.f, 0.f};

  // staging: call c stages 16B chunk p = c*256 + w*64 + lane
  //   row = (w&1)*64 + lane... careful: row = p & 127, kc = p >> 7
  const int rowS = ((w * 64 + lane) & 127);        // for c even base
  // for p = c*256 + w*64+lane: row = (w&1)*64 + lane if lane<64 ✓; kc = c*2 + (w>>1)
  const int kc0 = (w >> 1);
  const int lb0 = (0 * 256 + w * 64) * 8;
  const int lb1 = (1 * 256 + w * 64) * 8;

  for (int kk = 0; kk < DD; kk += 32) {
    glds16(aHi + (size_t)rowS * DD + kk + (kc0 + 0) * 8, sAhi + lb0);
    glds16(aHi + (size_t)rowS * DD + kk + (kc0 + 2) * 8, sAhi + lb1);
    glds16(aLo + (size_t)rowS * DD + kk + (kc0 + 0) * 8, sAlo + lb0);
    glds16(aLo + (size_t)rowS * DD + kk + (kc0 + 2) * 8, sAlo + lb1);
    glds16(bHi + (size_t)rowS * DD + kk + (kc0 + 0) * 8, sBhi + lb0);
    glds16(bHi + (size_t)rowS * DD + kk + (kc0 + 2) * 8, sBhi + lb1);
    glds16(bLo + (size_t)rowS * DD + kk + (kc0 + 0) * 8, sBlo + lb0);
    glds16(bLo + (size_t)rowS * DD + kk + (kc0 + 2) * 8, sBlo + lb1);
    __syncthreads();

    bf16x8 bh[4], bl[4];
#pragma unroll
    for (int tb = 0; tb < 4; ++tb) {
      int off = q * 1024 + (th + tb * 16 + fr) * 8;
      bh[tb] = *(const bf16x8*)&sBhi[off];
      bl[tb] = *(const bf16x8*)&sBlo[off];
    }
#pragma unroll
    for (int mb = 0; mb < 4; ++mb) {
      int off = q * 1024 + (nh + mb * 16 + fr) * 8;
      bf16x8 ah = *(const bf16x8*)&sAhi[off];
      bf16x8 al = *(const bf16x8*)&sAlo[off];
#pragma unroll
      for (int tb = 0; tb < 4; ++tb) {
        acc[mb][tb] = __builtin_amdgcn_mfma_f32_16x16x32_bf16(ah, bh[tb], acc[mb][tb], 0, 0, 0);
        acc[mb][tb] = __builtin_amdgcn_mfma_f32_16x16x32_bf16(ah, bl[tb], acc[mb][tb], 0, 0, 0);
        acc[mb][tb] = __builtin_amdgcn_mfma_f32_16x16x32_bf16(al, bh[tb], acc[mb][tb], 0, 0, 0);
      }
    }
    __syncthreads();
  }

  // epilogue: store scaled S + per-column (over this block's 128 n) stats
#pragma unroll
  for (int tb = 0; tb < 4; ++tb) {
    const int tl = th + tb * 16 + fr;       // 0..127
    const int t = t0 + tl;
    float tmp[16];
    float m = -FLT_MAX; int id = 0;
#pragma unroll
    for (int mb = 0; mb < 4; ++mb)
#pragma unroll
      for (int r = 0; r < 4; ++r) {
        float v = acc[mb][tb][r] * SCALE;
        int n = n0 + nh + mb * 16 + q * 4 + r;
        S[((size_t)b * NN + n) * TT + t] = v;
        tmp[mb * 4 + r] = v;
        int nl = nh + mb * 16 + q * 4 + r;
        if (v > m) { m = v; id = nl; }
      }
    float l = 0.f;
#pragma unroll
    for (int j = 0; j < 16; ++j) l += __expf(tmp[j] - m);
    // reduce across the 4 q-lane groups (same fr, same t)
#pragma unroll
    for (int off = 16; off <= 32; off <<= 1) {
      float m2 = __shfl_xor(m, off);
      float l2 = __shfl_xor(l, off);
      int i2 = __shfl_xor(id, off);
      if (m2 > m)       { l = l * __expf(m - m2) + l2; m = m2; id = i2; }
      else if (m2 == m) { l += l2; id = min(id, i2); }
      else              { l += l2 * __expf(m2 - m); }
    }
    if (q == 0) {
      int slot = (w & 1) * 128 + tl;
      sm[slot] = m; sl[slot] = l; si[slot] = id;
    }
  }
  __syncthreads();
  if (tid < 128) {
    float m = sm[tid], l = sl[tid]; int id = si[tid];         // nh=0 half
    float m2 = sm[128 + tid], l2 = sl[128 + tid]; int i2 = si[128 + tid];  // nh=64
    if (m2 > m)       { l = l * __expf(m - m2) + l2; m = m2; id = i2; }
    else if (m2 == m) { l += l2; id = min(id, i2); }
    else              { l += l2 * __expf(m2 - m); }
    size_t p = ((size_t)b * 32 + blockIdx.y) * TT + t0 + tid;
    mPart[p] = m; lPart[p] = l; iPart[p] = n0 + id;
  }
}

// ---------------- K2: combine 32 chunk partials ----------------
__global__ __launch_bounds__(256) void stats_final32(const float* __restrict__ mPart,
                                                     const float* __restrict__ lPart,
                                                     const int* __restrict__ iPart,
                                                     float* __restrict__ mArr,
                                                     float* __restrict__ rlArr,
                                                     float* __restrict__ outMax) {
  int col = blockIdx.x * 256 + threadIdx.x;  // b*T + t
  int b = col >> 10, t = col & 1023;
  float m = -FLT_MAX, l = 0.f;
  int idx = 0;
#pragma unroll 8
  for (int c = 0; c < 32; ++c) {
    size_t p = ((size_t)b * 32 + c) * TT + t;
    float m2 = mPart[p], l2 = lPart[p];
    int i2 = iPart[p];
    if (m2 > m)       { l = l * __expf(m - m2) + l2; m = m2; idx = i2; }
    else if (m2 == m) { l += l2; idx = min(idx, i2); }
    else              { l += l2 * __expf(m2 - m); }
  }
  mArr[col] = m;
  rlArr[col] = 1.0f / l;
  outMax[col] = (float)idx;
}

// ---------------- K3: fused  A=exp(S-m)*rl  +  Rpart = V @ A ----------------
// 256 thr (4 waves), tile: d=256 full, t=32, n-range 1024 (NSPLIT=4). grid (32,4,8)=1024 blocks
__global__ __launch_bounds__(256) void gemm_out_fused(const unsigned short* __restrict__ Vh,
                                                      float* __restrict__ A,   // in: raw S, out: normalized
                                                      const float* __restrict__ mArr,
                                                      const float* __restrict__ rlArr,
                                                      float* __restrict__ Rpart) {
  __shared__ short sV[256 * 32];    // [kc][d][8], 16 KB
  __shared__ short sA[32 * 40];     // [t][k] pad 40, 2.5 KB

  const int b = blockIdx.z, ny = blockIdx.y, t0 = blockIdx.x * 32;
  const int tid = threadIdx.x;
  const int lane = tid & 63, w = tid >> 6;
  const int fr = lane & 15, q = lane >> 4, fk = q * 8;

  const unsigned short* Vb = Vh + (size_t)b * DD * NN;
  float* Ab = A + (size_t)b * NN * TT;

  // per-thread S-staging mapping: n = tid>>3 (32 rows), t-group = tid&7
  const int sn = tid >> 3, tg = tid & 7;
  const int cb = b * TT + t0 + tg * 4;
  const float4 mv = *(const float4*)(mArr + cb);
  const float4 rv = *(const float4*)(rlArr + cb);

  // V staging: call c stages k-octet c for all 256 d; lane's d = w*64+lane
  const int vd = w * 64 + lane;

  f32x4 acc[4][2];
#pragma unroll
  for (int i = 0; i < 4; ++i) { acc[i][0] = (f32x4){0,0,0,0}; acc[i][1] = (f32x4){0,0,0,0}; }

  const int n0 = ny * 1024;
  for (int nn = n0; nn < n0 + 1024; nn += 32) {
#pragma unroll
    for (int c = 0; c < 4; ++c)
      glds16(Vb + (size_t)vd * NN + nn + c * 8, sV + (c * 256 + w * 64) * 8);

    float4 sv = *(const float4*)(Ab + (size_t)(nn + sn) * TT + t0 + tg * 4);
    float4 av;
    av.x = __expf(sv.x - mv.x) * rv.x;
    av.y = __expf(sv.y - mv.y) * rv.y;
    av.z = __expf(sv.z - mv.z) * rv.z;
    av.w = __expf(sv.w - mv.w) * rv.w;
    *(float4*)(Ab + (size_t)(nn + sn) * TT + t0 + tg * 4) = av;
    sA[(tg * 4 + 0) * 40 + sn] = (short)f2bf(av.x);
    sA[(tg * 4 + 1) * 40 + sn] = (short)f2bf(av.y);
    sA[(tg * 4 + 2) * 40 + sn] = (short)f2bf(av.z);
    sA[(tg * 4 + 3) * 40 + sn] = (short)f2bf(av.w);
    __syncthreads();

    bf16x8 bf0 = *(const bf16x8*)&sA[(0 * 16 + fr) * 40 + fk];
    bf16x8 bf1 = *(const bf16x8*)&sA[(1 * 16 + fr) * 40 + fk];
#pragma unroll
    for (int mb = 0; mb < 4; ++mb) {
      bf16x8 af = *(const bf16x8*)&sV[q * 2048 + (w * 64 + mb * 16 + fr) * 8];
      acc[mb][0] = __builtin_amdgcn_mfma_f32_16x16x32_bf16(af, bf0, acc[mb][0], 0, 0, 0);
      acc[mb][1] = __builtin_amdgcn_mfma_f32_16x16x32_bf16(af, bf1, acc[mb][1], 0, 0, 0);
    }
    __syncthreads();
  }

#pragma unroll
  for (int mb = 0; mb < 4; ++mb)
#pragma unroll
    for (int tb = 0; tb < 2; ++tb) {
      int t = t0 + tb * 16 + fr;
#pragma unroll
      for (int r = 0; r < 4; ++r) {
        int d = w * 64 + mb * 16 + q * 4 + r;
        Rpart[(((size_t)b * 4 + ny) * DD + d) * TT + t] = acc[mb][tb][r];
      }
    }
}

// ---------------- K4: R_ top = sum of 4 R partials; bottom = Q copy ----------------
__global__ __launch_bounds__(256) void combine(const float* __restrict__ Rpart,
                                               const float* __restrict__ Qp,
                                               float* __restrict__ out) {
  int g = blockIdx.x * 256 + threadIdx.x;   // 0..1048575
  int e = g * 4;
  int t = e & 1023;
  int row = e >> 10;        // 0..4095
  int d = row & 511, b = row >> 9;
  if (d < 256) {
    float4 s0 = *(const float4*)(Rpart + (((size_t)b * 4 + 0) * DD + d) * TT + t);
    float4 s1 = *(const float4*)(Rpart + (((size_t)b * 4 + 1) * DD + d) * TT + t);
    float4 s2 = *(const float4*)(Rpart + (((size_t)b * 4 + 2) * DD + d) * TT + t);
    float4 s3 = *(const float4*)(Rpart + (((size_t)b * 4 + 3) * DD + d) * TT + t);
    float4 r = make_float4(s0.x + s1.x + s2.x + s3.x, s0.y + s1.y + s2.y + s3.y,
                           s0.z + s1.z + s2.z + s3.z, s0.w + s1.w + s2.w + s3.w);
    *(float4*)(out + ((size_t)b * 512 + d) * TT + t) = r;
  } else {
    float4 v = *(const float4*)(Qp + ((size_t)b * 256 + (d - 256)) * TT + t);
    *(float4*)(out + ((size_t)b * 512 + d) * TT + t) = v;
  }
}

// =================== fp32 fallback path (ws too small) ===================
__global__ __launch_bounds__(256) void gemm_scores_fp32(const float* __restrict__ Kp,
                                                        const float* __restrict__ Qp,
                                                        float* __restrict__ S) {
  const int b = blockIdx.z;
  const int n0 = blockIdx.y * 128;
  const int t0 = blockIdx.x * 128;
  const int tid = threadIdx.x;
  const int tx = tid & 15, ty = tid >> 4;
  __shared__ float Kt[8][128];
  __shared__ float Qt[8][128];
  float acc[8][8];
#pragma unroll
  for (int i = 0; i < 8; ++i)
#pragma unroll
    for (int j = 0; j < 8; ++j) acc[i][j] = 0.f;
  const int lin = tid * 4;
  const int lkk = lin >> 7, lcol = lin & 127;
  const float* Kbase = Kp + (size_t)b * DD * NN;
  const float* Qbase = Qp + (size_t)b * DD * TT;
  for (int dd0 = 0; dd0 < DD; dd0 += 8) {
    float4 kv = *(const float4*)(Kbase + (size_t)(dd0 + lkk) * NN + n0 + lcol);
    float4 qv = *(const float4*)(Qbase + (size_t)(dd0 + lkk) * TT + t0 + lcol);
    __syncthreads();
    *(float4*)&Kt[lkk][lcol] = kv;
    *(float4*)&Qt[lkk][lcol] = qv;
    __syncthreads();
#pragma unroll
    for (int kk = 0; kk < 8; ++kk) {
      float4 a0 = *(float4*)&Kt[kk][ty * 4];
      float4 a1 = *(float4*)&Kt[kk][64 + ty * 4];
      float4 b0 = *(float4*)&Qt[kk][tx * 4];
      float4 b1 = *(float4*)&Qt[kk][64 + tx * 4];
      float av[8] = {a0.x, a0.y, a0.z, a0.w, a1.x, a1.y, a1.z, a1.w};
      float bv[8] = {b0.x, b0.y, b0.z, b0.w, b1.x, b1.y, b1.z, b1.w};
#pragma unroll
      for (int i = 0; i < 8; ++i)
#pragma unroll
        for (int j = 0; j < 8; ++j) acc[i][j] += av[i] * bv[j];
    }
  }
#pragma unroll
  for (int i = 0; i < 8; ++i) {
    int r = n0 + ((i < 4) ? (ty * 4 + i) : (64 + ty * 4 + i - 4));
    float* dst = S + ((size_t)b * NN + r) * TT + t0;
    *(float4*)(dst + tx * 4) = make_float4(acc[i][0] * SCALE, acc[i][1] * SCALE, acc[i][2] * SCALE, acc[i][3] * SCALE);
    *(float4*)(dst + 64 + tx * 4) = make_float4(acc[i][4] * SCALE, acc[i][5] * SCALE, acc[i][6] * SCALE, acc[i][7] * SCALE);
  }
}

__global__ __launch_bounds__(256) void stats_partial_fb(const float* __restrict__ S,
                                                        float* __restrict__ mPart,
                                                        float* __restrict__ lPart,
                                                        int* __restrict__ iPart) {
  const int tid = threadIdx.x;
  const int tx = tid & 63, ty = tid >> 6;
  const int b = blockIdx.z;
  const int t = blockIdx.x * 64 + tx;
  const int nbase = blockIdx.y * 512;
  float m = -FLT_MAX, l = 0.f;
  int idx = 0;
  const float* col = S + (size_t)b * NN * TT + t;
  for (int n = nbase + ty; n < nbase + 512; n += 4) {
    float s = col[(size_t)n * TT];
    if (s > m) { l = l * __expf(m - s) + 1.0f; m = s; idx = n; }
    else        l += __expf(s - m);
  }
  __shared__ float sm[4][64], sl[4][64];
  __shared__ int si[4][64];
  sm[ty][tx] = m; sl[ty][tx] = l; si[ty][tx] = idx;
  __syncthreads();
  if (ty == 0) {
#pragma unroll
    for (int k = 1; k < 4; ++k) {
      float m2 = sm[k][tx], l2 = sl[k][tx];
      int i2 = si[k][tx];
      if (m2 > m)       { l = l * __expf(m - m2) + l2; m = m2; idx = i2; }
      else if (m2 == m) { l += l2; idx = min(idx, i2); }
      else              { l += l2 * __expf(m2 - m); }
    }
    size_t p = (size_t)(b * 8 + blockIdx.y) * TT + t;
    mPart[p] = m; lPart[p] = l; iPart[p] = idx;
  }
}

__global__ __launch_bounds__(256) void stats_final_fb(const float* __restrict__ mPart,
                                                      const float* __restrict__ lPart,
                                                      const int* __restrict__ iPart,
                                                      float* __restrict__ mArr,
                                                      float* __restrict__ rlArr,
                                                      float* __restrict__ outMax) {
  int col = blockIdx.x * 256 + threadIdx.x;
  int b = col >> 10, t = col & 1023;
  float m = -FLT_MAX, l = 0.f;
  int idx = 0;
#pragma unroll
  for (int c = 0; c < 8; ++c) {
    size_t p = (size_t)(b * 8 + c) * TT + t;
    float m2 = mPart[p], l2 = lPart[p];
    int i2 = iPart[p];
    if (m2 > m)       { l = l * __expf(m - m2) + l2; m = m2; idx = i2; }
    else if (m2 == m) { l += l2; idx = min(idx, i2); }
    else              { l += l2 * __expf(m2 - m); }
  }
  mArr[col] = m;
  rlArr[col] = 1.0f / l;
  outMax[col] = (float)idx;
}

__global__ __launch_bounds__(256) void normalize_fb(float* __restrict__ A,
                                                    const float* __restrict__ mArr,
                                                    const float* __restrict__ rlArr) {
  int g = blockIdx.x * 256 + threadIdx.x;
  float4 s = ((const float4*)A)[g];
  int e = g * 4;
  int t0 = e & 1023;
  int row = e >> 10;
  int b = row >> 12;
  int cb = (b << 10) + t0;
  float4 r;
  r.x = __expf(s.x - mArr[cb + 0]) * rlArr[cb + 0];
  r.y = __expf(s.y - mArr[cb + 1]) * rlArr[cb + 1];
  r.z = __expf(s.z - mArr[cb + 2]) * rlArr[cb + 2];
  r.w = __expf(s.w - mArr[cb + 3]) * rlArr[cb + 3];
  ((float4*)A)[g] = r;
}

__global__ __launch_bounds__(256) void gemm_out_fp32(const float* __restrict__ Vp,
                                                     const float* __restrict__ A,
                                                     float* __restrict__ Rout) {
  const int b = blockIdx.z;
  const int m0 = blockIdx.y * 64;
  const int t0 = blockIdx.x * 128;
  const int tid = threadIdx.x;
  const int tx = tid & 15, ty = tid >> 4;
  __shared__ float Vt[16][68];
  __shared__ float At[16][128];
  float acc[4][8];
#pragma unroll
  for (int i = 0; i < 4; ++i)
#pragma unroll
    for (int j = 0; j < 8; ++j) acc[i][j] = 0.f;
  const float* Vbase = Vp + (size_t)b * DD * NN;
  const float* Abase = A + (size_t)b * NN * TT;
  const int vmm = tid >> 2, vkk = (tid & 3) * 4;
  const int akk = tid >> 5, att = (tid * 4) & 127;
  for (int nn0 = 0; nn0 < NN; nn0 += 16) {
    float4 vv = *(const float4*)(Vbase + (size_t)(m0 + vmm) * NN + nn0 + vkk);
    float4 a0 = *(const float4*)(Abase + (size_t)(nn0 + akk) * TT + t0 + att);
    float4 a1 = *(const float4*)(Abase + (size_t)(nn0 + akk + 8) * TT + t0 + att);
    __syncthreads();
    Vt[vkk + 0][vmm] = vv.x; Vt[vkk + 1][vmm] = vv.y;
    Vt[vkk + 2][vmm] = vv.z; Vt[vkk + 3][vmm] = vv.w;
    *(float4*)&At[akk][att] = a0;
    *(float4*)&At[akk + 8][att] = a1;
    __syncthreads();
#pragma unroll
    for (int kk = 0; kk < 16; ++kk) {
      float4 a4 = *(float4*)&Vt[kk][ty * 4];
      float4 b0 = *(float4*)&At[kk][tx * 4];
      float4 b1 = *(float4*)&At[kk][64 + tx * 4];
      float av[4] = {a4.x, a4.y, a4.z, a4.w};
      float bv[8] = {b0.x, b0.y, b0.z, b0.w, b1.x, b1.y, b1.z, b1.w};
#pragma unroll
      for (int i = 0; i < 4; ++i)
#pragma unroll
        for (int j = 0; j < 8; ++j) acc[i][j] += av[i] * bv[j];
    }
  }
#pragma unroll
  for (int i = 0; i < 4; ++i) {
    int r = m0 + ty * 4 + i;
    float* dst = Rout + (size_t)b * (2 * DD) * TT + (size_t)r * TT + t0;
    *(float4*)(dst + tx * 4) = make_float4(acc[i][0], acc[i][1], acc[i][2], acc[i][3]);
    *(float4*)(dst + 64 + tx * 4) = make_float4(acc[i][4], acc[i][5], acc[i][6], acc[i][7]);
  }
}

__global__ __launch_bounds__(256) void qcopy(const float* __restrict__ Qp,
                                             float* __restrict__ out) {
  int g = blockIdx.x * 256 + threadIdx.x;
  int e = g * 4;
  int t0 = e & 1023;
  int row = e >> 10;
  int dd = row & 255, b = row >> 8;
  float4 v = ((const float4*)Qp)[g];
  *(float4*)(out + (size_t)b * 512 * TT + (size_t)(256 + dd) * TT + t0) = v;
}

extern "C" void kernel_launch(void* const* d_in, const int* in_sizes, int n_in,
                              void* d_out, int out_size, void* d_ws, size_t ws_size,
                              hipStream_t stream) {
  const float* Kp = (const float*)d_in[0];
  const float* Vp = (const float*)d_in[1];
  const float* Qp = (const float*)d_in[2];
  float* out = (float*)d_out;
  float* R_ = out;
  float* A = out + 4194304;
  float* outMax = out + 4194304 + 33554432;

  char* wsb = (char*)d_ws;
  float* mPart = (float*)(wsb + MPART_OFF);
  float* lPart = (float*)(wsb + LPART_OFF);
  int*   iPart = (int*)(wsb + IPART_OFF);
  float* mArr  = (float*)(wsb + MARR_OFF);
  float* rlArr = (float*)(wsb + RLARR_OFF);

  const bool fast = (ws_size >= WS_NEED);

  if (fast) {
    unsigned short* KtHi = (unsigned short*)(wsb + KT_HI_OFF);
    unsigned short* KtLo = (unsigned short*)(wsb + KT_LO_OFF);
    unsigned short* QtHi = (unsigned short*)(wsb + QT_HI_OFF);
    unsigned short* QtLo = (unsigned short*)(wsb + QT_LO_OFF);
    unsigned short* Vh   = (unsigned short*)(wsb + VH_OFF);
    float* Rpart = (float*)(wsb + RPART_OFF);   // aliases Kt (dead after gemm_scores)

    convert_t<<<dim3(NN / 64, 4, BB), 256, 0, stream>>>(Kp, KtHi, KtLo, NN);
    convert_t<<<dim3(TT / 64, 4, BB), 256, 0, stream>>>(Qp, QtHi, QtLo, TT);
    convert_v<<<dim3((BB * DD * NN / 4) / 256), 256, 0, stream>>>(Vp, Vh);
    gemm_scores_mfma<<<dim3(TT / 128, NN / 128, BB), 256, 0, stream>>>(
        KtHi, KtLo, QtHi, QtLo, A, mPart, lPart, iPart);
    stats_final32<<<dim3(32), 256, 0, stream>>>(mPart, lPart, iPart, mArr, rlArr, outMax);
    gemm_out_fused<<<dim3(TT / 32, 4, BB), 256, 0, stream>>>(Vh, A, mArr, rlArr, Rpart);
    combine<<<dim3((BB * 512 * TT / 4) / 256), 256, 0, stream>>>(Rpart, Qp, R_);
  } else {
    gemm_scores_fp32<<<dim3(TT / 128, NN / 128, BB), 256, 0, stream>>>(Kp, Qp, A);
    stats_partial_fb<<<dim3(TT / 64, NN / 512, BB), 256, 0, stream>>>(A, mPart, lPart, iPart);
    stats_final_fb<<<dim3(32), 256, 0, stream>>>(mPart, lPart, iPart, mArr, rlArr, outMax);
    normalize_fb<<<dim3((BB * NN * TT / 4) / 256), 256, 0, stream>>>(A, mArr, rlArr);
    gemm_out_fp32<<<dim3(TT / 128, DD / 64, BB), 256, 0, stream>>>(Vp, A, R_);
    qcopy<<<dim3((BB * DD * TT / 4) / 256), 256, 0, stream>>>(Qp, R_);
  }
}